// Round 13
// baseline (2378.405 us; speedup 1.0000x reference)
//
#include <hip/hip_runtime.h>
#include <hip/hip_bf16.h>

constexpr int N1 = 4096;  // V rows
constexpr int D1 = 1024;  // visual dim
constexpr int N2 = 4096;  // X rows
constexpr int D2 = 4096;  // text dim

#define FNEG  (-3.402823466e+38f)
#define IDX_INF 0x7FFFFFFF
#define NCHUNK 32
#define CPR (NCHUNK * 6)     // 192 candidates per row

using s16x8 = __attribute__((ext_vector_type(8))) short;
using f32x4 = __attribute__((ext_vector_type(4))) float;
using f64x4 = __attribute__((ext_vector_type(4))) double;

static __device__ __forceinline__ unsigned short f2bf(float x) {
    unsigned int u = __float_as_uint(x);
    unsigned int r = (u + 0x7FFFu + ((u >> 16) & 1u)) >> 16;  // RNE
    return (unsigned short)r;
}
static __device__ __forceinline__ void splitbf(float x, unsigned short& h,
                                               unsigned short& l) {
    unsigned short hh = f2bf(x);
    float r = x - __uint_as_float((unsigned)hh << 16);
    h = hh; l = f2bf(r);
}
static __device__ __forceinline__ int swz(int row, int g) {
    return row * 32 + ((g ^ (row & 3)) << 3);
}

// stage 128x32 f32 tile -> split bf16 LDS (on-the-fly split)
static __device__ __forceinline__ void stageF32(const float* src, int ld,
    int rowbase, int k0, unsigned short* H, unsigned short* L, int tid)
{
    const int r = tid >> 1, half = tid & 1;
    const float* p = src + (size_t)(rowbase + r) * ld + k0 + half * 16;
#pragma unroll
    for (int gg = 0; gg < 2; ++gg) {
        const int g = half * 2 + gg;
        float4 v0 = *(const float4*)(p + gg * 8);
        float4 v1 = *(const float4*)(p + gg * 8 + 4);
        float xs[8] = {v0.x, v0.y, v0.z, v0.w, v1.x, v1.y, v1.z, v1.w};
        s16x8 hv, lv;
#pragma unroll
        for (int e = 0; e < 8; ++e) {
            unsigned short h, l; splitbf(xs[e], h, l);
            hv[e] = (short)h; lv[e] = (short)l;
        }
        const int a = swz(r, g);
        *(s16x8*)&H[a] = hv;
        *(s16x8*)&L[a] = lv;
    }
}

// stage 128x32 pre-split bf16 tile -> LDS (pure copy)
static __device__ __forceinline__ void stageSplit(const unsigned short* Hs,
    const unsigned short* Ls, int ld, int rowbase, int k0,
    unsigned short* H, unsigned short* L, int tid)
{
    const int r = tid >> 1, half = tid & 1;
    const unsigned short* ph = Hs + (size_t)(rowbase + r) * ld + k0 + half * 16;
    const unsigned short* pl = Ls + (size_t)(rowbase + r) * ld + k0 + half * 16;
#pragma unroll
    for (int gg = 0; gg < 2; ++gg) {
        const int g = half * 2 + gg;
        const int a = swz(r, g);
        *(s16x8*)&H[a] = *(const s16x8*)(ph + gg * 8);
        *(s16x8*)&L[a] = *(const s16x8*)(pl + gg * 8);
    }
}

static __device__ __forceinline__ void stageWvT(const float* Wv, int k0, int tn,
    unsigned short* H, unsigned short* L, int tid)
{
    const int kk = tid >> 3, cg = tid & 7;
    const int g = kk >> 3, idx = kk & 7;
    const float* p = Wv + (size_t)(k0 + kk) * D1 + tn + cg * 16;
#pragma unroll
    for (int q = 0; q < 4; ++q) {
        float4 v = *(const float4*)(p + q * 4);
        float xs[4] = {v.x, v.y, v.z, v.w};
#pragma unroll
        for (int e = 0; e < 4; ++e) {
            const int cc = cg * 16 + q * 4 + e;
            unsigned short h, l; splitbf(xs[e], h, l);
            const int a = cc * 32 + ((g ^ (cc & 3)) << 3) + idx;
            H[a] = h; L[a] = l;
        }
    }
}

static __device__ __forceinline__ s16x8 fragRead(const unsigned short* B,
                                                 int rowbase, int lane)
{
    const int row = rowbase + (lane & 15);
    const int g = lane >> 4;
    return *(const s16x8*)&B[row * 32 + ((g ^ (row & 3)) << 3)];
}

#define MFMA3(ACC, AH, AL, BH, BL)                                          \
    ACC = __builtin_amdgcn_mfma_f32_16x16x32_bf16(AH, BH, ACC, 0, 0, 0);    \
    ACC = __builtin_amdgcn_mfma_f32_16x16x32_bf16(AH, BL, ACC, 0, 0, 0);    \
    ACC = __builtin_amdgcn_mfma_f32_16x16x32_bf16(AL, BH, ACC, 0, 0, 0);

// ---------------------------------------------------------------------------
__global__ __launch_bounds__(256)
void kDetect(const float* c1, const float* c2, int* flags)
{
    __shared__ float red[256];
    float d = 0.f;
    for (int i = threadIdx.x; i < 4096; i += 256) {
        float a = c1[i], b = c2[i];
        d += a * a - b * b;
    }
    red[threadIdx.x] = d;
    __syncthreads();
    for (int st = 128; st > 0; st >>= 1) {
        if (threadIdx.x < st) red[threadIdx.x] += red[threadIdx.x + st];
        __syncthreads();
    }
    if (threadIdx.x == 0) flags[0] = (red[0] < 0.f) ? 1 : 0;
}

// ---------------------------------------------------------------------------
// Layout-discovering probe for v_mfma_f64_16x16x4 (round-12, verified pass).
__global__ __launch_bounds__(64)
void kProbe64(int* flags, int* rowmap)
{
    const int l = threadIdx.x;
    const f64x4 z = {0.0, 0.0, 0.0, 0.0};
    double av = (double)(l & 15);
    double ev = (double)(1 << (l >> 4));
    f64x4 c1 = __builtin_amdgcn_mfma_f64_16x16x4f64(av, 1.0, z, 0, 0, 0);
    f64x4 c2 = __builtin_amdgcn_mfma_f64_16x16x4f64(1.0, av, z, 0, 0, 0);
    f64x4 c3 = __builtin_amdgcn_mfma_f64_16x16x4f64(ev, ev, z, 0, 0, 0);

    bool ok = true;
    int im[4];
    unsigned cover = 0;
#pragma unroll
    for (int r = 0; r < 4; ++r) {
        int i = (int)(c1[r] * 0.25);
        ok = ok && (c1[r] == 4.0 * (double)i) && (i >= 0) && (i < 16);
        ok = ok && (c2[r] == 4.0 * (double)(l & 15));
        ok = ok && (c3[r] == 85.0);
        im[r] = i;
        cover |= (1u << (i & 15));
    }
#pragma unroll
    for (int r = 0; r < 4; ++r) {
        int x = im[r];
        ok = ok && (__shfl_xor(x, 1, 64) == x) && (__shfl_xor(x, 2, 64) == x) &&
                   (__shfl_xor(x, 4, 64) == x) && (__shfl_xor(x, 8, 64) == x);
    }
    int cv = (int)cover;
    cv |= __shfl_xor(cv, 16, 64);
    cv |= __shfl_xor(cv, 32, 64);
    ok = ok && ((unsigned)cv == 0xFFFFu);

    bool all = __all(ok);
    if ((l & 15) == 0) {
#pragma unroll
        for (int r = 0; r < 4; ++r) rowmap[(l >> 4) * 4 + r] = im[r];
    }
    if (l == 0) flags[1] = all ? 1 : 2;
}

// ---------------------------------------------------------------------------
// FUSED: Vp (f64 MFMA + norms) ∥ Z (split-bf16 MFMA) in one launch.
// Grid 1280 1D: bid%5==4 -> Z block (256 of them), else Vp block (1024).
// Independent inputs => overlap f64 matrix pipe with Z's VALU staging.
__global__ __launch_bounds__(256)
void kFusedVpZ(const float* c1, const float* c2, const float* bv,
               const float* X, const int* flags, const int* rowmap,
               double* Vpd, double* partial,
               unsigned short* Zh, unsigned short* Zl)
{
    __shared__ double poolD[4608];   // 36864 B, max(Vp 36864, Z 32768)
    char* pool = (char*)poolD;
    const int bid = blockIdx.x;
    const int tid = threadIdx.x;
    const int lane = tid & 63, w = tid >> 6;
    const int wr = w >> 1, wc = w & 1;

    if (bid % 5 != 4) {
        // ================= Vp role (f64 MFMA) =================
        if (flags[1] != 1) return;   // probe failed -> kVpGemm fallback
        const int vid = (bid / 5) * 4 + (bid % 5);
        const int by = vid >> 5, bx = vid & 31;
        const float* V  = flags[0] ? c2 : c1;
        const float* Wv = flags[0] ? c1 : c2;
        double* Vs = poolD;                       // [128*17]
        double* Ws = poolD + 2176;                // [128*17]
        double (*partH)[2] = (double(*)[2])(poolD + 4352);  // [128][2]
        const int tm = by * 128;
        const int tn = bx * 128;
        const int n4 = lane & 15, kg = lane >> 4;

        int rmap[4];
#pragma unroll
        for (int r = 0; r < 4; ++r) rmap[r] = rowmap[kg * 4 + r];

        f64x4 acc[4][4];
#pragma unroll
        for (int i = 0; i < 4; ++i)
#pragma unroll
            for (int j = 0; j < 4; ++j) acc[i][j] = (f64x4){0.0, 0.0, 0.0, 0.0};

        for (int k0 = 0; k0 < D1; k0 += 16) {
            {
                const int r = tid >> 1, half = tid & 1;
                const float* pv = V  + (size_t)(tm + r) * D1 + k0 + half * 8;
                const float* pw = Wv + (size_t)(tn + r) * D1 + k0 + half * 8;
                float4 v0 = *(const float4*)(pv);
                float4 v1 = *(const float4*)(pv + 4);
                float4 w0 = *(const float4*)(pw);
                float4 w1 = *(const float4*)(pw + 4);
                float xv[8] = {v0.x, v0.y, v0.z, v0.w, v1.x, v1.y, v1.z, v1.w};
                float xw[8] = {w0.x, w0.y, w0.z, w0.w, w1.x, w1.y, w1.z, w1.w};
#pragma unroll
                for (int e = 0; e < 8; ++e) {
                    Vs[r * 17 + half * 8 + e] = (double)xv[e];
                    Ws[r * 17 + half * 8 + e] = (double)xw[e];
                }
            }
            __syncthreads();
#pragma unroll
            for (int k4 = 0; k4 < 4; ++k4) {
                double a[4], b[4];
#pragma unroll
                for (int f = 0; f < 4; ++f) {
                    a[f] = Vs[(wr * 64 + f * 16 + n4) * 17 + k4 * 4 + kg];
                    b[f] = Ws[(wc * 64 + f * 16 + n4) * 17 + k4 * 4 + kg];
                }
#pragma unroll
                for (int fm = 0; fm < 4; ++fm)
#pragma unroll
                    for (int fn = 0; fn < 4; ++fn)
                        acc[fm][fn] = __builtin_amdgcn_mfma_f64_16x16x4f64(
                            a[fm], b[fn], acc[fm][fn], 0, 0, 0);
            }
            __syncthreads();
        }

        double bvv[4];
#pragma unroll
        for (int fn = 0; fn < 4; ++fn)
            bvv[fn] = (double)bv[tn + wc * 64 + fn * 16 + n4];
#pragma unroll
        for (int fm = 0; fm < 4; ++fm)
#pragma unroll
            for (int rr = 0; rr < 4; ++rr) {
                const int lrow = wr * 64 + fm * 16 + rmap[rr];
                double rs = 0.0;
#pragma unroll
                for (int fn = 0; fn < 4; ++fn) {
                    double v = acc[fm][fn][rr] + bvv[fn];
                    Vpd[(size_t)(tm + lrow) * D2 +
                        (tn + wc * 64 + fn * 16 + n4)] = v;
                    rs += v * v;
                }
#pragma unroll
                for (int off = 1; off < 16; off <<= 1)
                    rs += __shfl_xor(rs, off, 64);
                if (n4 == 0) partH[lrow][wc] = rs;
            }
        __syncthreads();
        if (tid < 128)
            partial[(size_t)(tm + tid) * 32 + bx] =
                partH[tid][0] + partH[tid][1];
    } else {
        // ================= Z role (split-bf16 MFMA) =================
        const int zid = bid / 5;
        const int by = zid >> 3, bx = zid & 7;
        const float* Wv = flags[0] ? c1 : c2;
        unsigned short* AH = (unsigned short*)pool;
        unsigned short* AL = (unsigned short*)(pool + 8192);
        unsigned short* BH = (unsigned short*)(pool + 16384);
        unsigned short* BL = (unsigned short*)(pool + 24576);
        const int tm = by * 128;
        const int tn = bx * 128;

        f32x4 acc[4][4];
#pragma unroll
        for (int i = 0; i < 4; ++i)
#pragma unroll
            for (int j = 0; j < 4; ++j) acc[i][j] = (f32x4){0.f, 0.f, 0.f, 0.f};

        for (int k0 = 0; k0 < D2; k0 += 32) {
            stageF32(X, D2, tm, k0, AH, AL, tid);
            stageWvT(Wv, k0, tn, BH, BL, tid);
            __syncthreads();
            s16x8 ah[4], al[4], bh[4], bl[4];
#pragma unroll
            for (int f = 0; f < 4; ++f) {
                ah[f] = fragRead(AH, wr * 64 + f * 16, lane);
                al[f] = fragRead(AL, wr * 64 + f * 16, lane);
                bh[f] = fragRead(BH, wc * 64 + f * 16, lane);
                bl[f] = fragRead(BL, wc * 64 + f * 16, lane);
            }
#pragma unroll
            for (int fm = 0; fm < 4; ++fm)
#pragma unroll
                for (int fn = 0; fn < 4; ++fn) {
                    MFMA3(acc[fm][fn], ah[fm], al[fm], bh[fn], bl[fn]);
                }
            __syncthreads();
        }
#pragma unroll
        for (int fm = 0; fm < 4; ++fm)
#pragma unroll
            for (int fn = 0; fn < 4; ++fn)
#pragma unroll
                for (int r = 0; r < 4; ++r) {
                    int row = tm + wr * 64 + fm * 16 + (lane >> 4) * 4 + r;
                    int col = tn + wc * 64 + fn * 16 + (lane & 15);
                    unsigned short h, l;
                    splitbf(acc[fm][fn][r], h, l);
                    size_t o = (size_t)row * D1 + col;
                    Zh[o] = h; Zl[o] = l;
                }
    }
}

// ---------------------------------------------------------------------------
// Fallback (probe failed): SIMT f64 Vp GEMM.
__global__ __launch_bounds__(256)
void kVpGemm(const float* c1, const float* c2, const float* bv,
             const int* flags, double* Vpd, double* partial)
{
    if (flags[1] == 1) return;
    const float* V  = flags[0] ? c2 : c1;
    const float* Wv = flags[0] ? c1 : c2;
    __shared__ float As[16 * 132];
    __shared__ float Bs[16 * 132];
    __shared__ double Rsq[128 * 17];
    const int tid = threadIdx.x;
    const int tx = tid & 15, ty = tid >> 4;
    const int tm = blockIdx.y * 128;
    const int tn = blockIdx.x * 128;

    double acc[8][8];
#pragma unroll
    for (int i = 0; i < 8; ++i)
#pragma unroll
        for (int j = 0; j < 8; ++j) acc[i][j] = 0.0;

    for (int k0 = 0; k0 < D1; k0 += 16) {
#pragma unroll
        for (int p = 0; p < 2; ++p) {
            int idx = tid + p * 256;
            int row = idx >> 2;
            int kc  = (idx & 3) << 2;
            float4 va = *(const float4*)(V + (size_t)(tm + row) * D1 + k0 + kc);
            As[(kc + 0) * 132 + row] = va.x;
            As[(kc + 1) * 132 + row] = va.y;
            As[(kc + 2) * 132 + row] = va.z;
            As[(kc + 3) * 132 + row] = va.w;
            float4 vb = *(const float4*)(Wv + (size_t)(tn + row) * D1 + k0 + kc);
            Bs[(kc + 0) * 132 + row] = vb.x;
            Bs[(kc + 1) * 132 + row] = vb.y;
            Bs[(kc + 2) * 132 + row] = vb.z;
            Bs[(kc + 3) * 132 + row] = vb.w;
        }
        __syncthreads();
#pragma unroll 4
        for (int kk = 0; kk < 16; ++kk) {
            float af[8], bf[8];
            *(float4*)&af[0] = *(const float4*)&As[kk * 132 + ty * 8];
            *(float4*)&af[4] = *(const float4*)&As[kk * 132 + ty * 8 + 4];
            *(float4*)&bf[0] = *(const float4*)&Bs[kk * 132 + tx * 8];
            *(float4*)&bf[4] = *(const float4*)&Bs[kk * 132 + tx * 8 + 4];
            double a[8], b[8];
#pragma unroll
            for (int i = 0; i < 8; ++i) { a[i] = (double)af[i]; b[i] = (double)bf[i]; }
#pragma unroll
            for (int i = 0; i < 8; ++i)
#pragma unroll
                for (int j = 0; j < 8; ++j)
                    acc[i][j] = fma(a[i], b[j], acc[i][j]);
        }
        __syncthreads();
    }
#pragma unroll
    for (int i = 0; i < 8; ++i) {
        double rs = 0.0;
#pragma unroll
        for (int j = 0; j < 8; ++j) {
            double v = acc[i][j] + (double)bv[tn + tx * 8 + j];
            Vpd[(size_t)(tm + ty * 8 + i) * D2 + (tn + tx * 8 + j)] = v;
            rs += v * v;
        }
        Rsq[(ty * 8 + i) * 17 + tx] = rs;
    }
    __syncthreads();
    if (tid < 128) {
        double s = 0.0;
        for (int x = 0; x < 16; ++x) s += Rsq[tid * 17 + x];
        partial[(size_t)(tm + tid) * 32 + blockIdx.x] = s;
    }
}

__global__ __launch_bounds__(256)
void kSvec(const float* X, const float* bv, double* sX, float* sXF)
{
    __shared__ double red[256];
    const int row = blockIdx.x;
    double s = 0.0;
    for (int n = threadIdx.x; n < D2; n += 256)
        s += (double)X[(size_t)row * D2 + n] * (double)bv[n];
    red[threadIdx.x] = s;
    __syncthreads();
    for (int st = 128; st > 0; st >>= 1) {
        if (threadIdx.x < st) red[threadIdx.x] += red[threadIdx.x + st];
        __syncthreads();
    }
    if (threadIdx.x == 0) { sX[row] = red[0]; sXF[row] = (float)red[0]; }
}

__global__ __launch_bounds__(256)
void kInv(const double* partial, double* invn, float* invnF)
{
    int j = blockIdx.x * 256 + threadIdx.x;
    double s = 0.0;
    for (int cb = 0; cb < 32; ++cb) s += partial[(size_t)j * 32 + cb];
    double iv = 1.0 / (sqrt(s) + 1e-8);
    invn[j] = iv;
    invnF[j] = (float)iv;
}

// ---------------------------------------------------------------------------
static __device__ __forceinline__ void top6f(float v, int i, float* vv, int* ii)
{
#pragma unroll
    for (int s = 0; s < 6; ++s) {
        if (v > vv[s]) {
#pragma unroll
            for (int t = 5; t > s; --t) { vv[t] = vv[t-1]; ii[t] = ii[t-1]; }
            vv[s] = v; ii[s] = i;
            break;
        }
    }
}

// mfmaS: scores = Z @ V^T (A from pre-split Zh/Zl) + top-6 epilogue
__global__ __launch_bounds__(256)
void mfmaS(const unsigned short* Zh, const unsigned short* Zl,
           const float* c1, const float* c2,
           const float* invnF, const float* sXF, const int* flags,
           float* candV, int* candI)
{
    const float* V = flags[0] ? c2 : c1;
    __shared__ __align__(16) char pool[41472];
    unsigned short* AH = (unsigned short*)pool;
    unsigned short* AL = (unsigned short*)(pool + 8192);
    unsigned short* BH = (unsigned short*)(pool + 16384);
    unsigned short* BL = (unsigned short*)(pool + 24576);
    float* Ct   = (float*)pool;
    float* pv   = (float*)(pool + 33792);
    int*   pi   = (int*)  (pool + 36864);
    float* invs = (float*)(pool + 39936);

    const int tid = threadIdx.x;
    const int lane = tid & 63, w = tid >> 6;
    const int wr = w >> 1, wc = w & 1;
    const int tm = blockIdx.y * 128;
    const int tn = blockIdx.x * 128;

    f32x4 acc[4][4];
#pragma unroll
    for (int i = 0; i < 4; ++i)
#pragma unroll
        for (int j = 0; j < 4; ++j) acc[i][j] = (f32x4){0.f, 0.f, 0.f, 0.f};

    for (int k0 = 0; k0 < D1; k0 += 32) {
        stageSplit(Zh, Zl, D1, tm, k0, AH, AL, tid);
        stageF32(V, D1, tn, k0, BH, BL, tid);
        __syncthreads();
        s16x8 ah[4], al[4], bh[4], bl[4];
#pragma unroll
        for (int f = 0; f < 4; ++f) {
            ah[f] = fragRead(AH, wr * 64 + f * 16, lane);
            al[f] = fragRead(AL, wr * 64 + f * 16, lane);
            bh[f] = fragRead(BH, wc * 64 + f * 16, lane);
            bl[f] = fragRead(BL, wc * 64 + f * 16, lane);
        }
#pragma unroll
        for (int fm = 0; fm < 4; ++fm)
#pragma unroll
            for (int fn = 0; fn < 4; ++fn) {
                MFMA3(acc[fm][fn], ah[fm], al[fm], bh[fn], bl[fn]);
            }
        __syncthreads();
    }

    if (tid < 128) invs[tid] = invnF[tn + tid];
    for (int h = 0; h < 2; ++h) {
        __syncthreads();
        if (wr == h) {
#pragma unroll
            for (int fm = 0; fm < 4; ++fm)
#pragma unroll
                for (int fn = 0; fn < 4; ++fn)
#pragma unroll
                    for (int r = 0; r < 4; ++r) {
                        int lr = fm * 16 + (lane >> 4) * 4 + r;
                        int c  = wc * 64 + fn * 16 + (lane & 15);
                        Ct[lr * 132 + c] = acc[fm][fn][r];
                    }
        }
        __syncthreads();
        if (tid < 128) {
            int r = tid >> 1, seg = tid & 1;
            float sxf = sXF[tm + h * 64 + r];
            float vv[6]; int ii[6];
#pragma unroll
            for (int s = 0; s < 6; ++s) { vv[s] = FNEG; ii[s] = IDX_INF; }
            for (int cc = 0; cc < 64; ++cc) {
                int c = seg * 64 + cc;
                float v = (Ct[r * 132 + c] + sxf) * invs[c];
                top6f(v, tn + c, vv, ii);
            }
#pragma unroll
            for (int s = 0; s < 6; ++s) {
                pv[(r * 2 + seg) * 6 + s] = vv[s];
                pi[(r * 2 + seg) * 6 + s] = ii[s];
            }
        }
        __syncthreads();
        if (tid < 64) {
            float vv[6]; int ii[6];
#pragma unroll
            for (int s = 0; s < 6; ++s) { vv[s] = FNEG; ii[s] = IDX_INF; }
            for (int seg = 0; seg < 2; ++seg)
                for (int s = 0; s < 6; ++s)
                    top6f(pv[(tid * 2 + seg) * 6 + s],
                          pi[(tid * 2 + seg) * 6 + s], vv, ii);
            int row = tm + h * 64 + tid;
#pragma unroll
            for (int s = 0; s < 6; ++s) {
                candV[(size_t)row * CPR + blockIdx.x * 6 + s] = vv[s];
                candI[(size_t)row * CPR + blockIdx.x * 6 + s] = ii[s];
            }
        }
    }
}

// ---------------------------------------------------------------------------
__global__ __launch_bounds__(256)
void kRefineVp(const float* candV, const int* candI,
               const double* Vpd, const float* X,
               const double* invn, int* tidx)
{
    __shared__ int    fi[6];
    __shared__ double sv[6];
    __shared__ double red[256];
    const int row = blockIdx.x;
    const int tid = threadIdx.x;

    if (tid == 0) {
        float vv[6]; int ii[6];
        for (int s = 0; s < 6; ++s) { vv[s] = FNEG; ii[s] = IDX_INF; }
        for (int c = 0; c < CPR; ++c)
            top6f(candV[(size_t)row * CPR + c], candI[(size_t)row * CPR + c], vv, ii);
        for (int s = 0; s < 6; ++s) fi[s] = ii[s];
    }
    __syncthreads();

    const float* x = X + (size_t)row * D2;
    for (int s = 0; s < 6; ++s) {
        const int j = fi[s];
        const double* vp = Vpd + (size_t)j * D2;
        double p = 0.0;
        for (int c = tid; c < D2; c += 256) p += (double)x[c] * vp[c];
        red[tid] = p;
        __syncthreads();
        for (int st = 128; st > 0; st >>= 1) {
            if (tid < st) red[tid] += red[tid + st];
            __syncthreads();
        }
        if (tid == 0) sv[s] = red[0] * invn[j];
        __syncthreads();
    }

    if (tid == 0) {
        int ord[6] = {0,1,2,3,4,5};
        for (int a = 0; a < 5; ++a)
            for (int b = a + 1; b < 6; ++b) {
                bool swp = (sv[ord[b]] > sv[ord[a]]) ||
                           (sv[ord[b]] == sv[ord[a]] && fi[ord[b]] < fi[ord[a]]);
                if (swp) { int t = ord[a]; ord[a] = ord[b]; ord[b] = t; }
            }
        tidx[row * 3 + 0] = fi[ord[0]];
        tidx[row * 3 + 1] = fi[ord[1]];
        tidx[row * 3 + 2] = fi[ord[2]];
    }
}

// kGatherU: U = w0*V[i0]+w1*V[i1]+w2*V[i2], emitted PRE-SPLIT (Uh/Ul)
__global__ __launch_bounds__(256)
void kGatherU(const float* c1, const float* c2, const int* flags,
              const int* tidx, const float* Wf,
              unsigned short* Uh, unsigned short* Ul)
{
    const float* V = flags[0] ? c2 : c1;
    const int row = blockIdx.x;
    const int i0 = tidx[row*3+0], i1 = tidx[row*3+1], i2 = tidx[row*3+2];
    const float w0 = Wf[0], w1 = Wf[1], w2 = Wf[2];
    for (int c = threadIdx.x; c < D1; c += 256) {
        float a = V[(size_t)i0 * D1 + c];
        float b = V[(size_t)i1 * D1 + c];
        float d = V[(size_t)i2 * D1 + c];
        float u = w0 * a + w1 * b + w2 * d;
        unsigned short h, l; splitbf(u, h, l);
        Uh[(size_t)row * D1 + c] = h;
        Ul[(size_t)row * D1 + c] = l;
    }
}

__global__ __launch_bounds__(256)
void kAux2(const float* Wf, const float* bfp, const float* bv, float* aux2)
{
    int c = blockIdx.x * 256 + threadIdx.x;
    float sw = Wf[0] + Wf[1] + Wf[2];
    aux2[c] = sw * bv[c] + bfp[0];
}

// mfmaU + X-copy fused: blocks [0,1024) = U tiles; [1024,1280) copy X->outX
__global__ __launch_bounds__(256)
void mfmaUX(const unsigned short* Uh, const unsigned short* Ul,
            const float* c1, const float* c2, const int* flags,
            const float* aux2, const float* X, float* out0, float* outX)
{
    const int bid = blockIdx.x;
    const int tid = threadIdx.x;
    if (bid >= 1024) {
        // copy 64 MiB of X in 256 blocks x 256 KiB
        const int cb = bid - 1024;
        const float4* src = (const float4*)(X + (size_t)cb * 65536);
        float4* dst = (float4*)(outX + (size_t)cb * 65536);
        for (int i = tid; i < 16384; i += 256) dst[i] = src[i];
        return;
    }
    const float* Wv = flags[0] ? c1 : c2;
    __shared__ unsigned short AH[4096], AL[4096], BH[4096], BL[4096];
    const int lane = tid & 63, w = tid >> 6;
    const int wr = w >> 1, wc = w & 1;
    const int tm = (bid >> 5) * 128;
    const int tn = (bid & 31) * 128;

    f32x4 acc[4][4];
#pragma unroll
    for (int i = 0; i < 4; ++i)
#pragma unroll
        for (int j = 0; j < 4; ++j) acc[i][j] = (f32x4){0.f, 0.f, 0.f, 0.f};

    for (int k0 = 0; k0 < D1; k0 += 32) {
        stageSplit(Uh, Ul, D1, tm, k0, AH, AL, tid);
        stageF32(Wv, D1, tn, k0, BH, BL, tid);
        __syncthreads();
        s16x8 ah[4], al[4], bh[4], bl[4];
#pragma unroll
        for (int f = 0; f < 4; ++f) {
            ah[f] = fragRead(AH, wr * 64 + f * 16, lane);
            al[f] = fragRead(AL, wr * 64 + f * 16, lane);
            bh[f] = fragRead(BH, wc * 64 + f * 16, lane);
            bl[f] = fragRead(BL, wc * 64 + f * 16, lane);
        }
#pragma unroll
        for (int fm = 0; fm < 4; ++fm)
#pragma unroll
            for (int fn = 0; fn < 4; ++fn) {
                MFMA3(acc[fm][fn], ah[fm], al[fm], bh[fn], bl[fn]);
            }
        __syncthreads();
    }
#pragma unroll
    for (int fm = 0; fm < 4; ++fm)
#pragma unroll
        for (int fn = 0; fn < 4; ++fn)
#pragma unroll
            for (int r = 0; r < 4; ++r) {
                int row = tm + wr * 64 + fm * 16 + (lane >> 4) * 4 + r;
                int col = tn + wc * 64 + fn * 16 + (lane & 15);
                out0[(size_t)row * D2 + col] = acc[fm][fn][r] + aux2[col];
            }
}

// ---------------------------------------------------------------------------
extern "C" void kernel_launch(void* const* d_in, const int* in_sizes, int n_in,
                              void* d_out, int out_size, void* d_ws, size_t ws_size,
                              hipStream_t stream)
{
    const float *c1 = nullptr, *c2 = nullptr, *X = nullptr;
    const float *bv = nullptr, *Wf = nullptr, *bfp = nullptr;
    for (int i = 0; i < n_in; ++i) {
        const float* p = (const float*)d_in[i];
        switch (in_sizes[i]) {
            case 16777216: X = p; break;
            case 4194304:  if (!c1) c1 = p; else c2 = p; break;
            case 4096:     bv = p; break;
            case 3:        Wf = p; break;
            case 1:        bfp = p; break;
            default: break;
        }
    }

    float* out_f = (float*)d_out;       // f32 [8192,4096] = 128 MiB
    float* outVa = out_f;
    float* outX  = out_f + (size_t)N2 * D2;
    int*   flags  = (int*)d_ws;
    int*   rowmap = (int*)((char*)d_ws + 64);

    char* C0 = (char*)d_ws + 1024;
    double* sX    = (double*)(C0);                   // 32 KiB
    double* invn  = (double*)(C0 + 32768);           // 32 KiB
    float*  sXF   = (float*) (C0 + 65536);           // 16 KiB
    float*  invnF = (float*) (C0 + 81920);           // 16 KiB
    int*    tidx  = (int*)   (C0 + 98304);           // 48 KiB
    float*  aux2  = (float*) (C0 + 147456);          // 16 KiB
    double* part  = (double*)(C0 + 163840);          // 1 MiB
    float*  candV = (float*) (C0 + 1212416);         // 3 MiB
    int*    candI = (int*)   (C0 + 4358144);         // 3 MiB
    unsigned short* Zh = (unsigned short*)(C0 + 7503872);   // 8 MiB
    unsigned short* Zl = Zh + (size_t)N2 * D1;              // 8 MiB
    unsigned short* Uh = Zh;   // overlay after mfmaS
    unsigned short* Ul = Zl;
    double* Vpd = (double*)d_out;                    // 128 MiB (phase 1)

    kDetect<<<1, 256, 0, stream>>>(c1, c2, flags);
    kProbe64<<<1, 64, 0, stream>>>(flags, rowmap);
    kSvec<<<N2, 256, 0, stream>>>(X, bv, sX, sXF);

    // Fused Vp (f64 MFMA) ∥ Z (bf16 MFMA): 1024 + 256 interleaved blocks
    kFusedVpZ<<<1280, 256, 0, stream>>>(c1, c2, bv, X, flags, rowmap,
                                        Vpd, part, Zh, Zl);
    // Fallback for Vp if the f64 probe failed (dormant when probe passes)
    dim3 gVp(D2 / 128, N1 / 128);
    kVpGemm<<<gVp, 256, 0, stream>>>(c1, c2, bv, flags, Vpd, part);

    kInv<<<16, 256, 0, stream>>>(part, invn, invnF);

    dim3 gS(N1 / 128, N2 / 128);     // (32, 32)
    mfmaS<<<gS, 256, 0, stream>>>(Zh, Zl, c1, c2, invnF, sXF, flags,
                                  candV, candI);

    kRefineVp<<<N2, 256, 0, stream>>>(candV, candI, Vpd, X, invn, tidx);
    kGatherU<<<N2, 256, 0, stream>>>(c1, c2, flags, tidx, Wf, Uh, Ul);
    kAux2<<<16, 256, 0, stream>>>(Wf, bfp, bv, aux2);

    // mfmaU tiles + X->outX copy in one launch (Vpd dead after refine)
    mfmaUX<<<1280, 256, 0, stream>>>(Uh, Ul, c1, c2, flags, aux2, X,
                                     outVa, outX);
}

// Round 14
// 1906.072 us; speedup vs baseline: 1.2478x; 1.2478x over previous
//
#include <hip/hip_runtime.h>
#include <hip/hip_bf16.h>

constexpr int N1 = 4096;  // V rows
constexpr int D1 = 1024;  // visual dim
constexpr int N2 = 4096;  // X rows
constexpr int D2 = 4096;  // text dim

#define FNEG  (-3.402823466e+38f)
#define IDX_INF 0x7FFFFFFF
#define NCHUNK 32
#define CPR (NCHUNK * 6)     // 192 candidates per row

using s16x8 = __attribute__((ext_vector_type(8))) short;
using f32x4 = __attribute__((ext_vector_type(4))) float;
using f64x4 = __attribute__((ext_vector_type(4))) double;

static __device__ __forceinline__ unsigned short f2bf(float x) {
    unsigned int u = __float_as_uint(x);
    unsigned int r = (u + 0x7FFFu + ((u >> 16) & 1u)) >> 16;  // RNE
    return (unsigned short)r;
}
static __device__ __forceinline__ void splitbf(float x, unsigned short& h,
                                               unsigned short& l) {
    unsigned short hh = f2bf(x);
    float r = x - __uint_as_float((unsigned)hh << 16);
    h = hh; l = f2bf(r);
}
static __device__ __forceinline__ int swz(int row, int g) {
    return row * 32 + ((g ^ (row & 3)) << 3);
}

// stage 128x32 f32 tile -> split bf16 LDS (on-the-fly split)
static __device__ __forceinline__ void stageF32(const float* src, int ld,
    int rowbase, int k0, unsigned short* H, unsigned short* L, int tid)
{
    const int r = tid >> 1, half = tid & 1;
    const float* p = src + (size_t)(rowbase + r) * ld + k0 + half * 16;
#pragma unroll
    for (int gg = 0; gg < 2; ++gg) {
        const int g = half * 2 + gg;
        float4 v0 = *(const float4*)(p + gg * 8);
        float4 v1 = *(const float4*)(p + gg * 8 + 4);
        float xs[8] = {v0.x, v0.y, v0.z, v0.w, v1.x, v1.y, v1.z, v1.w};
        s16x8 hv, lv;
#pragma unroll
        for (int e = 0; e < 8; ++e) {
            unsigned short h, l; splitbf(xs[e], h, l);
            hv[e] = (short)h; lv[e] = (short)l;
        }
        const int a = swz(r, g);
        *(s16x8*)&H[a] = hv;
        *(s16x8*)&L[a] = lv;
    }
}

// stage 128x32 pre-split bf16 tile -> LDS (pure copy)
static __device__ __forceinline__ void stageSplit(const unsigned short* Hs,
    const unsigned short* Ls, int ld, int rowbase, int k0,
    unsigned short* H, unsigned short* L, int tid)
{
    const int r = tid >> 1, half = tid & 1;
    const unsigned short* ph = Hs + (size_t)(rowbase + r) * ld + k0 + half * 16;
    const unsigned short* pl = Ls + (size_t)(rowbase + r) * ld + k0 + half * 16;
#pragma unroll
    for (int gg = 0; gg < 2; ++gg) {
        const int g = half * 2 + gg;
        const int a = swz(r, g);
        *(s16x8*)&H[a] = *(const s16x8*)(ph + gg * 8);
        *(s16x8*)&L[a] = *(const s16x8*)(pl + gg * 8);
    }
}

static __device__ __forceinline__ void stageWvT(const float* Wv, int k0, int tn,
    unsigned short* H, unsigned short* L, int tid)
{
    const int kk = tid >> 3, cg = tid & 7;
    const int g = kk >> 3, idx = kk & 7;
    const float* p = Wv + (size_t)(k0 + kk) * D1 + tn + cg * 16;
#pragma unroll
    for (int q = 0; q < 4; ++q) {
        float4 v = *(const float4*)(p + q * 4);
        float xs[4] = {v.x, v.y, v.z, v.w};
#pragma unroll
        for (int e = 0; e < 4; ++e) {
            const int cc = cg * 16 + q * 4 + e;
            unsigned short h, l; splitbf(xs[e], h, l);
            const int a = cc * 32 + ((g ^ (cc & 3)) << 3) + idx;
            H[a] = h; L[a] = l;
        }
    }
}

static __device__ __forceinline__ s16x8 fragRead(const unsigned short* B,
                                                 int rowbase, int lane)
{
    const int row = rowbase + (lane & 15);
    const int g = lane >> 4;
    return *(const s16x8*)&B[row * 32 + ((g ^ (row & 3)) << 3)];
}

#define MFMA3(ACC, AH, AL, BH, BL)                                          \
    ACC = __builtin_amdgcn_mfma_f32_16x16x32_bf16(AH, BH, ACC, 0, 0, 0);    \
    ACC = __builtin_amdgcn_mfma_f32_16x16x32_bf16(AH, BL, ACC, 0, 0, 0);    \
    ACC = __builtin_amdgcn_mfma_f32_16x16x32_bf16(AL, BH, ACC, 0, 0, 0);

// ---------------------------------------------------------------------------
__global__ __launch_bounds__(256)
void kDetect(const float* c1, const float* c2, int* flags)
{
    __shared__ float red[256];
    float d = 0.f;
    for (int i = threadIdx.x; i < 4096; i += 256) {
        float a = c1[i], b = c2[i];
        d += a * a - b * b;
    }
    red[threadIdx.x] = d;
    __syncthreads();
    for (int st = 128; st > 0; st >>= 1) {
        if (threadIdx.x < st) red[threadIdx.x] += red[threadIdx.x + st];
        __syncthreads();
    }
    if (threadIdx.x == 0) flags[0] = (red[0] < 0.f) ? 1 : 0;
}

// ---------------------------------------------------------------------------
// Layout-discovering probe for v_mfma_f64_16x16x4 (round-12, verified pass).
__global__ __launch_bounds__(64)
void kProbe64(int* flags, int* rowmap)
{
    const int l = threadIdx.x;
    const f64x4 z = {0.0, 0.0, 0.0, 0.0};
    double av = (double)(l & 15);
    double ev = (double)(1 << (l >> 4));
    f64x4 c1 = __builtin_amdgcn_mfma_f64_16x16x4f64(av, 1.0, z, 0, 0, 0);
    f64x4 c2 = __builtin_amdgcn_mfma_f64_16x16x4f64(1.0, av, z, 0, 0, 0);
    f64x4 c3 = __builtin_amdgcn_mfma_f64_16x16x4f64(ev, ev, z, 0, 0, 0);

    bool ok = true;
    int im[4];
    unsigned cover = 0;
#pragma unroll
    for (int r = 0; r < 4; ++r) {
        int i = (int)(c1[r] * 0.25);
        ok = ok && (c1[r] == 4.0 * (double)i) && (i >= 0) && (i < 16);
        ok = ok && (c2[r] == 4.0 * (double)(l & 15));
        ok = ok && (c3[r] == 85.0);
        im[r] = i;
        cover |= (1u << (i & 15));
    }
#pragma unroll
    for (int r = 0; r < 4; ++r) {
        int x = im[r];
        ok = ok && (__shfl_xor(x, 1, 64) == x) && (__shfl_xor(x, 2, 64) == x) &&
                   (__shfl_xor(x, 4, 64) == x) && (__shfl_xor(x, 8, 64) == x);
    }
    int cv = (int)cover;
    cv |= __shfl_xor(cv, 16, 64);
    cv |= __shfl_xor(cv, 32, 64);
    ok = ok && ((unsigned)cv == 0xFFFFu);

    bool all = __all(ok);
    if ((l & 15) == 0) {
#pragma unroll
        for (int r = 0; r < 4; ++r) rowmap[(l >> 4) * 4 + r] = im[r];
    }
    if (l == 0) flags[1] = all ? 1 : 2;
}

// ---------------------------------------------------------------------------
// mfmaVp v2: Vpd = V@Wv^T + bv (f64 MFMA, exact) + fused norm partials.
// 512 threads = 8 waves, each wave owns 64x32 (fm 0..3 x fn 0..1).
// acc = 8 x f64x4 = 64 VGPR -> higher occupancy than round-12's 128.
// LDS staged as f32 (exact convert at read): 21.5 KB. Vpd bitwise == round-12.
__global__ __launch_bounds__(512)
void mfmaVp(const float* c1, const float* c2, const float* bv,
            const int* flags, const int* rowmap, double* Vpd, double* partial)
{
    if (flags[1] != 1) return;
    const float* V  = flags[0] ? c2 : c1;
    const float* Wv = flags[0] ? c1 : c2;
    __shared__ float Vs[128 * 17];
    __shared__ float Ws[128 * 17];
    __shared__ double partH[128][4];
    const int tid = threadIdx.x;
    const int lane = tid & 63, w = tid >> 6;
    const int wr = w >> 2, wc = w & 3;     // wave tile: rows wr*64, cols wc*32
    const int tm = blockIdx.y * 128;       // V rows (j)
    const int tn = blockIdx.x * 128;       // n cols
    const int n4 = lane & 15, kg = lane >> 4;

    int rmap[4];
#pragma unroll
    for (int r = 0; r < 4; ++r) rmap[r] = rowmap[kg * 4 + r];

    f64x4 acc[4][2];
#pragma unroll
    for (int i = 0; i < 4; ++i)
#pragma unroll
        for (int j = 0; j < 2; ++j) acc[i][j] = (f64x4){0.0, 0.0, 0.0, 0.0};

    for (int k0 = 0; k0 < D1; k0 += 16) {
        {   // stage: 512 threads x 4 f32 per operand (f32 LDS, pad 17)
            const int r = tid >> 2, q = (tid & 3) * 4;
            float4 va = *(const float4*)(V  + (size_t)(tm + r) * D1 + k0 + q);
            float4 vb = *(const float4*)(Wv + (size_t)(tn + r) * D1 + k0 + q);
            Vs[r * 17 + q + 0] = va.x; Vs[r * 17 + q + 1] = va.y;
            Vs[r * 17 + q + 2] = va.z; Vs[r * 17 + q + 3] = va.w;
            Ws[r * 17 + q + 0] = vb.x; Ws[r * 17 + q + 1] = vb.y;
            Ws[r * 17 + q + 2] = vb.z; Ws[r * 17 + q + 3] = vb.w;
        }
        __syncthreads();
#pragma unroll
        for (int k4 = 0; k4 < 4; ++k4) {
            double a[4], b[2];
#pragma unroll
            for (int f = 0; f < 4; ++f)
                a[f] = (double)Vs[(wr * 64 + f * 16 + n4) * 17 + k4 * 4 + kg];
#pragma unroll
            for (int f = 0; f < 2; ++f)
                b[f] = (double)Ws[(wc * 32 + f * 16 + n4) * 17 + k4 * 4 + kg];
#pragma unroll
            for (int fm = 0; fm < 4; ++fm)
#pragma unroll
                for (int fn = 0; fn < 2; ++fn)
                    acc[fm][fn] = __builtin_amdgcn_mfma_f64_16x16x4f64(
                        a[fm], b[fn], acc[fm][fn], 0, 0, 0);
        }
        __syncthreads();
    }

    // epilogue: bias add, Vpd store, norm partials
    double bvv[2];
#pragma unroll
    for (int fn = 0; fn < 2; ++fn)
        bvv[fn] = (double)bv[tn + wc * 32 + fn * 16 + n4];
#pragma unroll
    for (int fm = 0; fm < 4; ++fm)
#pragma unroll
        for (int rr = 0; rr < 4; ++rr) {
            const int lrow = wr * 64 + fm * 16 + rmap[rr];
            double rs = 0.0;
#pragma unroll
            for (int fn = 0; fn < 2; ++fn) {
                double v = acc[fm][fn][rr] + bvv[fn];
                Vpd[(size_t)(tm + lrow) * D2 +
                    (tn + wc * 32 + fn * 16 + n4)] = v;
                rs += v * v;
            }
#pragma unroll
            for (int off = 1; off < 16; off <<= 1)
                rs += __shfl_xor(rs, off, 64);
            if (n4 == 0) partH[lrow][wc] = rs;
        }
    __syncthreads();
    if (tid < 128)
        partial[(size_t)(tm + tid) * 32 + blockIdx.x] =
            partH[tid][0] + partH[tid][1] + partH[tid][2] + partH[tid][3];
}

// ---------------------------------------------------------------------------
// Fallback (probe failed): SIMT f64 Vp GEMM.
__global__ __launch_bounds__(256)
void kVpGemm(const float* c1, const float* c2, const float* bv,
             const int* flags, double* Vpd, double* partial)
{
    if (flags[1] == 1) return;
    const float* V  = flags[0] ? c2 : c1;
    const float* Wv = flags[0] ? c1 : c2;
    __shared__ float As[16 * 132];
    __shared__ float Bs[16 * 132];
    __shared__ double Rsq[128 * 17];
    const int tid = threadIdx.x;
    const int tx = tid & 15, ty = tid >> 4;
    const int tm = blockIdx.y * 128;
    const int tn = blockIdx.x * 128;

    double acc[8][8];
#pragma unroll
    for (int i = 0; i < 8; ++i)
#pragma unroll
        for (int j = 0; j < 8; ++j) acc[i][j] = 0.0;

    for (int k0 = 0; k0 < D1; k0 += 16) {
#pragma unroll
        for (int p = 0; p < 2; ++p) {
            int idx = tid + p * 256;
            int row = idx >> 2;
            int kc  = (idx & 3) << 2;
            float4 va = *(const float4*)(V + (size_t)(tm + row) * D1 + k0 + kc);
            As[(kc + 0) * 132 + row] = va.x;
            As[(kc + 1) * 132 + row] = va.y;
            As[(kc + 2) * 132 + row] = va.z;
            As[(kc + 3) * 132 + row] = va.w;
            float4 vb = *(const float4*)(Wv + (size_t)(tn + row) * D1 + k0 + kc);
            Bs[(kc + 0) * 132 + row] = vb.x;
            Bs[(kc + 1) * 132 + row] = vb.y;
            Bs[(kc + 2) * 132 + row] = vb.z;
            Bs[(kc + 3) * 132 + row] = vb.w;
        }
        __syncthreads();
#pragma unroll 4
        for (int kk = 0; kk < 16; ++kk) {
            float af[8], bf[8];
            *(float4*)&af[0] = *(const float4*)&As[kk * 132 + ty * 8];
            *(float4*)&af[4] = *(const float4*)&As[kk * 132 + ty * 8 + 4];
            *(float4*)&bf[0] = *(const float4*)&Bs[kk * 132 + tx * 8];
            *(float4*)&bf[4] = *(const float4*)&Bs[kk * 132 + tx * 8 + 4];
            double a[8], b[8];
#pragma unroll
            for (int i = 0; i < 8; ++i) { a[i] = (double)af[i]; b[i] = (double)bf[i]; }
#pragma unroll
            for (int i = 0; i < 8; ++i)
#pragma unroll
                for (int j = 0; j < 8; ++j)
                    acc[i][j] = fma(a[i], b[j], acc[i][j]);
        }
        __syncthreads();
    }
#pragma unroll
    for (int i = 0; i < 8; ++i) {
        double rs = 0.0;
#pragma unroll
        for (int j = 0; j < 8; ++j) {
            double v = acc[i][j] + (double)bv[tn + tx * 8 + j];
            Vpd[(size_t)(tm + ty * 8 + i) * D2 + (tn + tx * 8 + j)] = v;
            rs += v * v;
        }
        Rsq[(ty * 8 + i) * 17 + tx] = rs;
    }
    __syncthreads();
    if (tid < 128) {
        double s = 0.0;
        for (int x = 0; x < 16; ++x) s += Rsq[tid * 17 + x];
        partial[(size_t)(tm + tid) * 32 + blockIdx.x] = s;
    }
}

__global__ __launch_bounds__(256)
void kSvec(const float* X, const float* bv, double* sX, float* sXF)
{
    __shared__ double red[256];
    const int row = blockIdx.x;
    double s = 0.0;
    for (int n = threadIdx.x; n < D2; n += 256)
        s += (double)X[(size_t)row * D2 + n] * (double)bv[n];
    red[threadIdx.x] = s;
    __syncthreads();
    for (int st = 128; st > 0; st >>= 1) {
        if (threadIdx.x < st) red[threadIdx.x] += red[threadIdx.x + st];
        __syncthreads();
    }
    if (threadIdx.x == 0) { sX[row] = red[0]; sXF[row] = (float)red[0]; }
}

__global__ __launch_bounds__(256)
void kInv(const double* partial, double* invn, float* invnF)
{
    int j = blockIdx.x * 256 + threadIdx.x;
    double s = 0.0;
    for (int cb = 0; cb < 32; ++cb) s += partial[(size_t)j * 32 + cb];
    double iv = 1.0 / (sqrt(s) + 1e-8);
    invn[j] = iv;
    invnF[j] = (float)iv;
}

// ---------------------------------------------------------------------------
// mfmaZ: Z = X @ Wv (split-bf16 MFMA) -> PRE-SPLIT output Zh/Zl (bf16 pair)
__global__ __launch_bounds__(256)
void mfmaZ(const float* X, const float* c1, const float* c2, const int* flags,
           unsigned short* Zh, unsigned short* Zl)
{
    const float* Wv = flags[0] ? c1 : c2;
    __shared__ unsigned short AH[4096], AL[4096], BH[4096], BL[4096];
    const int tid = threadIdx.x;
    const int lane = tid & 63, w = tid >> 6;
    const int wr = w >> 1, wc = w & 1;
    const int tm = blockIdx.y * 128;
    const int tn = blockIdx.x * 128;

    f32x4 acc[4][4];
#pragma unroll
    for (int i = 0; i < 4; ++i)
#pragma unroll
        for (int j = 0; j < 4; ++j) acc[i][j] = (f32x4){0.f, 0.f, 0.f, 0.f};

    for (int k0 = 0; k0 < D2; k0 += 32) {
        stageF32(X, D2, tm, k0, AH, AL, tid);
        stageWvT(Wv, k0, tn, BH, BL, tid);
        __syncthreads();
        s16x8 ah[4], al[4], bh[4], bl[4];
#pragma unroll
        for (int f = 0; f < 4; ++f) {
            ah[f] = fragRead(AH, wr * 64 + f * 16, lane);
            al[f] = fragRead(AL, wr * 64 + f * 16, lane);
            bh[f] = fragRead(BH, wc * 64 + f * 16, lane);
            bl[f] = fragRead(BL, wc * 64 + f * 16, lane);
        }
#pragma unroll
        for (int fm = 0; fm < 4; ++fm)
#pragma unroll
            for (int fn = 0; fn < 4; ++fn) {
                MFMA3(acc[fm][fn], ah[fm], al[fm], bh[fn], bl[fn]);
            }
        __syncthreads();
    }
#pragma unroll
    for (int fm = 0; fm < 4; ++fm)
#pragma unroll
        for (int fn = 0; fn < 4; ++fn)
#pragma unroll
            for (int r = 0; r < 4; ++r) {
                int row = tm + wr * 64 + fm * 16 + (lane >> 4) * 4 + r;
                int col = tn + wc * 64 + fn * 16 + (lane & 15);
                unsigned short h, l;
                splitbf(acc[fm][fn][r], h, l);
                size_t o = (size_t)row * D1 + col;
                Zh[o] = h; Zl[o] = l;
            }
}

// ---------------------------------------------------------------------------
static __device__ __forceinline__ void top6f(float v, int i, float* vv, int* ii)
{
#pragma unroll
    for (int s = 0; s < 6; ++s) {
        if (v > vv[s]) {
#pragma unroll
            for (int t = 5; t > s; --t) { vv[t] = vv[t-1]; ii[t] = ii[t-1]; }
            vv[s] = v; ii[s] = i;
            break;
        }
    }
}

// mfmaS: scores = Z @ V^T (A from pre-split Zh/Zl) + top-6 epilogue
__global__ __launch_bounds__(256)
void mfmaS(const unsigned short* Zh, const unsigned short* Zl,
           const float* c1, const float* c2,
           const float* invnF, const float* sXF, const int* flags,
           float* candV, int* candI)
{
    const float* V = flags[0] ? c2 : c1;
    __shared__ __align__(16) char pool[41472];
    unsigned short* AH = (unsigned short*)pool;
    unsigned short* AL = (unsigned short*)(pool + 8192);
    unsigned short* BH = (unsigned short*)(pool + 16384);
    unsigned short* BL = (unsigned short*)(pool + 24576);
    float* Ct   = (float*)pool;
    float* pv   = (float*)(pool + 33792);
    int*   pi   = (int*)  (pool + 36864);
    float* invs = (float*)(pool + 39936);

    const int tid = threadIdx.x;
    const int lane = tid & 63, w = tid >> 6;
    const int wr = w >> 1, wc = w & 1;
    const int tm = blockIdx.y * 128;
    const int tn = blockIdx.x * 128;

    f32x4 acc[4][4];
#pragma unroll
    for (int i = 0; i < 4; ++i)
#pragma unroll
        for (int j = 0; j < 4; ++j) acc[i][j] = (f32x4){0.f, 0.f, 0.f, 0.f};

    for (int k0 = 0; k0 < D1; k0 += 32) {
        stageSplit(Zh, Zl, D1, tm, k0, AH, AL, tid);
        stageF32(V, D1, tn, k0, BH, BL, tid);
        __syncthreads();
        s16x8 ah[4], al[4], bh[4], bl[4];
#pragma unroll
        for (int f = 0; f < 4; ++f) {
            ah[f] = fragRead(AH, wr * 64 + f * 16, lane);
            al[f] = fragRead(AL, wr * 64 + f * 16, lane);
            bh[f] = fragRead(BH, wc * 64 + f * 16, lane);
            bl[f] = fragRead(BL, wc * 64 + f * 16, lane);
        }
#pragma unroll
        for (int fm = 0; fm < 4; ++fm)
#pragma unroll
            for (int fn = 0; fn < 4; ++fn) {
                MFMA3(acc[fm][fn], ah[fm], al[fm], bh[fn], bl[fn]);
            }
        __syncthreads();
    }

    if (tid < 128) invs[tid] = invnF[tn + tid];
    for (int h = 0; h < 2; ++h) {
        __syncthreads();
        if (wr == h) {
#pragma unroll
            for (int fm = 0; fm < 4; ++fm)
#pragma unroll
                for (int fn = 0; fn < 4; ++fn)
#pragma unroll
                    for (int r = 0; r < 4; ++r) {
                        int lr = fm * 16 + (lane >> 4) * 4 + r;
                        int c  = wc * 64 + fn * 16 + (lane & 15);
                        Ct[lr * 132 + c] = acc[fm][fn][r];
                    }
        }
        __syncthreads();
        if (tid < 128) {
            int r = tid >> 1, seg = tid & 1;
            float sxf = sXF[tm + h * 64 + r];
            float vv[6]; int ii[6];
#pragma unroll
            for (int s = 0; s < 6; ++s) { vv[s] = FNEG; ii[s] = IDX_INF; }
            for (int cc = 0; cc < 64; ++cc) {
                int c = seg * 64 + cc;
                float v = (Ct[r * 132 + c] + sxf) * invs[c];
                top6f(v, tn + c, vv, ii);
            }
#pragma unroll
            for (int s = 0; s < 6; ++s) {
                pv[(r * 2 + seg) * 6 + s] = vv[s];
                pi[(r * 2 + seg) * 6 + s] = ii[s];
            }
        }
        __syncthreads();
        if (tid < 64) {
            float vv[6]; int ii[6];
#pragma unroll
            for (int s = 0; s < 6; ++s) { vv[s] = FNEG; ii[s] = IDX_INF; }
            for (int seg = 0; seg < 2; ++seg)
                for (int s = 0; s < 6; ++s)
                    top6f(pv[(tid * 2 + seg) * 6 + s],
                          pi[(tid * 2 + seg) * 6 + s], vv, ii);
            int row = tm + h * 64 + tid;
#pragma unroll
            for (int s = 0; s < 6; ++s) {
                candV[(size_t)row * CPR + blockIdx.x * 6 + s] = vv[s];
                candI[(size_t)row * CPR + blockIdx.x * 6 + s] = ii[s];
            }
        }
    }
}

// ---------------------------------------------------------------------------
__global__ __launch_bounds__(256)
void kRefineVp(const float* candV, const int* candI,
               const double* Vpd, const float* X,
               const double* invn, int* tidx)
{
    __shared__ int    fi[6];
    __shared__ double sv[6];
    __shared__ double red[256];
    const int row = blockIdx.x;
    const int tid = threadIdx.x;

    if (tid == 0) {
        float vv[6]; int ii[6];
        for (int s = 0; s < 6; ++s) { vv[s] = FNEG; ii[s] = IDX_INF; }
        for (int c = 0; c < CPR; ++c)
            top6f(candV[(size_t)row * CPR + c], candI[(size_t)row * CPR + c], vv, ii);
        for (int s = 0; s < 6; ++s) fi[s] = ii[s];
    }
    __syncthreads();

    const float* x = X + (size_t)row * D2;
    for (int s = 0; s < 6; ++s) {
        const int j = fi[s];
        const double* vp = Vpd + (size_t)j * D2;
        double p = 0.0;
        for (int c = tid; c < D2; c += 256) p += (double)x[c] * vp[c];
        red[tid] = p;
        __syncthreads();
        for (int st = 128; st > 0; st >>= 1) {
            if (tid < st) red[tid] += red[tid + st];
            __syncthreads();
        }
        if (tid == 0) sv[s] = red[0] * invn[j];
        __syncthreads();
    }

    if (tid == 0) {
        int ord[6] = {0,1,2,3,4,5};
        for (int a = 0; a < 5; ++a)
            for (int b = a + 1; b < 6; ++b) {
                bool swp = (sv[ord[b]] > sv[ord[a]]) ||
                           (sv[ord[b]] == sv[ord[a]] && fi[ord[b]] < fi[ord[a]]);
                if (swp) { int t = ord[a]; ord[a] = ord[b]; ord[b] = t; }
            }
        tidx[row * 3 + 0] = fi[ord[0]];
        tidx[row * 3 + 1] = fi[ord[1]];
        tidx[row * 3 + 2] = fi[ord[2]];
    }
}

// kGatherU: U = w0*V[i0]+w1*V[i1]+w2*V[i2], emitted PRE-SPLIT (Uh/Ul)
__global__ __launch_bounds__(256)
void kGatherU(const float* c1, const float* c2, const int* flags,
              const int* tidx, const float* Wf,
              unsigned short* Uh, unsigned short* Ul)
{
    const float* V = flags[0] ? c2 : c1;
    const int row = blockIdx.x;
    const int i0 = tidx[row*3+0], i1 = tidx[row*3+1], i2 = tidx[row*3+2];
    const float w0 = Wf[0], w1 = Wf[1], w2 = Wf[2];
    for (int c = threadIdx.x; c < D1; c += 256) {
        float a = V[(size_t)i0 * D1 + c];
        float b = V[(size_t)i1 * D1 + c];
        float d = V[(size_t)i2 * D1 + c];
        float u = w0 * a + w1 * b + w2 * d;
        unsigned short h, l; splitbf(u, h, l);
        Uh[(size_t)row * D1 + c] = h;
        Ul[(size_t)row * D1 + c] = l;
    }
}

__global__ __launch_bounds__(256)
void kAux2(const float* Wf, const float* bfp, const float* bv, float* aux2)
{
    int c = blockIdx.x * 256 + threadIdx.x;
    float sw = Wf[0] + Wf[1] + Wf[2];
    aux2[c] = sw * bv[c] + bfp[0];
}

// mfmaU: out0 = U @ Wv^T + aux2 (A from pre-split Uh/Ul)
__global__ __launch_bounds__(256)
void mfmaU(const unsigned short* Uh, const unsigned short* Ul,
           const float* c1, const float* c2, const int* flags,
           const float* aux2, float* out0)
{
    const float* Wv = flags[0] ? c1 : c2;
    __shared__ unsigned short AH[4096], AL[4096], BH[4096], BL[4096];
    const int tid = threadIdx.x;
    const int lane = tid & 63, w = tid >> 6;
    const int wr = w >> 1, wc = w & 1;
    const int tm = blockIdx.y * 128;
    const int tn = blockIdx.x * 128;

    f32x4 acc[4][4];
#pragma unroll
    for (int i = 0; i < 4; ++i)
#pragma unroll
        for (int j = 0; j < 4; ++j) acc[i][j] = (f32x4){0.f, 0.f, 0.f, 0.f};

    for (int k0 = 0; k0 < D1; k0 += 32) {
        stageSplit(Uh, Ul, D1, tm, k0, AH, AL, tid);
        stageF32(Wv, D1, tn, k0, BH, BL, tid);
        __syncthreads();
        s16x8 ah[4], al[4], bh[4], bl[4];
#pragma unroll
        for (int f = 0; f < 4; ++f) {
            ah[f] = fragRead(AH, wr * 64 + f * 16, lane);
            al[f] = fragRead(AL, wr * 64 + f * 16, lane);
            bh[f] = fragRead(BH, wc * 64 + f * 16, lane);
            bl[f] = fragRead(BL, wc * 64 + f * 16, lane);
        }
#pragma unroll
        for (int fm = 0; fm < 4; ++fm)
#pragma unroll
            for (int fn = 0; fn < 4; ++fn) {
                MFMA3(acc[fm][fn], ah[fm], al[fm], bh[fn], bl[fn]);
            }
        __syncthreads();
    }
#pragma unroll
    for (int fm = 0; fm < 4; ++fm)
#pragma unroll
        for (int fn = 0; fn < 4; ++fn)
#pragma unroll
            for (int r = 0; r < 4; ++r) {
                int row = tm + wr * 64 + fm * 16 + (lane >> 4) * 4 + r;
                int col = tn + wc * 64 + fn * 16 + (lane & 15);
                out0[(size_t)row * D2 + col] = acc[fm][fn][r] + aux2[col];
            }
}

// ---------------------------------------------------------------------------
extern "C" void kernel_launch(void* const* d_in, const int* in_sizes, int n_in,
                              void* d_out, int out_size, void* d_ws, size_t ws_size,
                              hipStream_t stream)
{
    const float *c1 = nullptr, *c2 = nullptr, *X = nullptr;
    const float *bv = nullptr, *Wf = nullptr, *bfp = nullptr;
    for (int i = 0; i < n_in; ++i) {
        const float* p = (const float*)d_in[i];
        switch (in_sizes[i]) {
            case 16777216: X = p; break;
            case 4194304:  if (!c1) c1 = p; else c2 = p; break;
            case 4096:     bv = p; break;
            case 3:        Wf = p; break;
            case 1:        bfp = p; break;
            default: break;
        }
    }

    float* out_f = (float*)d_out;       // f32 [8192,4096] = 128 MiB
    float* outVa = out_f;
    float* outX  = out_f + (size_t)N2 * D2;
    int*   flags  = (int*)d_ws;
    int*   rowmap = (int*)((char*)d_ws + 64);

    char* C0 = (char*)d_ws + 1024;
    double* sX    = (double*)(C0);                   // 32 KiB
    double* invn  = (double*)(C0 + 32768);           // 32 KiB
    float*  sXF   = (float*) (C0 + 65536);           // 16 KiB
    float*  invnF = (float*) (C0 + 81920);           // 16 KiB
    int*    tidx  = (int*)   (C0 + 98304);           // 48 KiB
    float*  aux2  = (float*) (C0 + 147456);          // 16 KiB
    double* part  = (double*)(C0 + 163840);          // 1 MiB
    float*  candV = (float*) (C0 + 1212416);         // 3 MiB
    int*    candI = (int*)   (C0 + 4358144);         // 3 MiB
    unsigned short* Zh = (unsigned short*)(C0 + 7503872);   // 8 MiB
    unsigned short* Zl = Zh + (size_t)N2 * D1;              // 8 MiB
    unsigned short* Uh = Zh;   // overlay after mfmaS
    unsigned short* Ul = Zl;
    double* Vpd = (double*)d_out;                    // 128 MiB (phase 1)

    kDetect<<<1, 256, 0, stream>>>(c1, c2, flags);
    kProbe64<<<1, 64, 0, stream>>>(flags, rowmap);

    dim3 gVp(D2 / 128, N1 / 128);    // (32, 32)
    mfmaVp<<<gVp, 512, 0, stream>>>(c1, c2, bv, flags, rowmap, Vpd, part);
    kVpGemm<<<gVp, 256, 0, stream>>>(c1, c2, bv, flags, Vpd, part);
    kInv<<<16, 256, 0, stream>>>(part, invn, invnF);
    kSvec<<<N2, 256, 0, stream>>>(X, bv, sX, sXF);

    dim3 gZ(D1 / 128, N2 / 128);     // (8, 32)
    mfmaZ<<<gZ, 256, 0, stream>>>(X, c1, c2, flags, Zh, Zl);

    dim3 gS(N1 / 128, N2 / 128);     // (32, 32)
    mfmaS<<<gS, 256, 0, stream>>>(Zh, Zl, c1, c2, invnF, sXF, flags,
                                  candV, candI);

    kRefineVp<<<N2, 256, 0, stream>>>(candV, candI, Vpd, X, invn, tidx);
    kGatherU<<<N2, 256, 0, stream>>>(c1, c2, flags, tidx, Wf, Uh, Ul);
    kAux2<<<16, 256, 0, stream>>>(Wf, bfp, bv, aux2);

    dim3 gU(D2 / 128, N2 / 128);     // (32, 32)
    mfmaU<<<gU, 256, 0, stream>>>(Uh, Ul, c1, c2, flags, aux2, outVa);

    hipMemcpyAsync(outX, X, (size_t)N2 * D2 * sizeof(float),
                   hipMemcpyDeviceToDevice, stream);
}